// Round 1
// 336.681 us; speedup vs baseline: 1.0692x; 1.0692x over previous
//
#include <hip/hip_runtime.h>

// TemporalEmbedding: out = concat(emb0[i0], emb1[i1], emb2[i2], pe) @ W + b
// Split-K table GEMM (partials) -> reduce(+bias, +T01 combine) -> l-major gather-add.
//
// P row layout (2367 rows x 512), written by te_gemm_partial (UNCHANGED from prev round):
//   rows 0..6     : T0 = emb0 @ W[0:512]
//   rows 7..30    : T1 = emb1 @ W[512:1024]
//   rows 31..318  : T2 = emb2 @ W[1024:1536]
//   rows 319..2366: Tp = pe[:2048] @ W[1536:2048]   (bias added in reduce)
//
// T row layout (2504 rows x 512), written by te_reduce:
//   rows 0..167   : T01[i0*24+i1] = T0[i0] + T1[i1]   (344 KB)
//   rows 168..455 : T2                                  (576 KB)
//   rows 456..2503: Tp + bias                           (4 MB)
// Hot random-read set for the gather = T01+T2 = 920 KB -> L2-resident per XCD.
//
// Workspace (floats):
//   T at 0                 : 2504 x 512             (5.1 MB)
//   P at 2504*512          : 4 x 2367 x 512         (19.4 MB)  split-K partials

#define TM 32
#define TN 64
#define TK 16
#define KSPLIT 4
#define PROWS 2367
#define TROWS 2504

// clang-native vector type for __builtin_nontemporal_store
typedef float vfloat4 __attribute__((ext_vector_type(4)));

__global__ __launch_bounds__(256) void te_gemm_partial(
    const float* __restrict__ emb0, const float* __restrict__ emb1,
    const float* __restrict__ emb2, const float* __restrict__ pe,
    const float* __restrict__ W, float* __restrict__ P)
{
    // grid: x = 8 n-tiles, y = 75 m-tiles (1 + 1 + 9 + 64), z = 4 k-splits
    __shared__ float As[TK][TM + 4];   // [k][m]
    __shared__ float Bs[TK][TN + 4];   // [k][n]

    const int nt  = blockIdx.x;
    const int mt  = blockIdx.y;
    const int kz  = blockIdx.z;
    const int tid = threadIdx.x;

    const float* A; int M; int m0; int wrow; int tbase;
    if (mt == 0)       { A = emb0; M = 7;    m0 = 0;            wrow = 0;    tbase = 0;   }
    else if (mt == 1)  { A = emb1; M = 24;   m0 = 0;            wrow = 512;  tbase = 7;   }
    else if (mt < 11)  { A = emb2; M = 288;  m0 = (mt-2)*TM;    wrow = 1024; tbase = 31;  }
    else               { A = pe;   M = 2048; m0 = (mt-11)*TM;   wrow = 1536; tbase = 319; }

    const int n0 = nt * TN;
    const int kbase = kz * 128;   // this block's K range: [kbase, kbase+128)

    // staging coords
    const int ar = tid >> 2;          // 0..63 (only 0..31 used for A rows)
    const int ac = (tid & 3) * 4;     // k offset (float4)
    const int br = tid >> 4;          // 0..15 : B k-row
    const int bc = (tid & 15) * 4;    // n offset (float4)

    // compute coords: 2x4 outputs per thread
    const int my = (tid >> 4) * 2;    // 0..30
    const int mx = (tid & 15) * 4;    // 0..60

    float acc[2][4];
    #pragma unroll
    for (int i = 0; i < 2; i++)
        #pragma unroll
        for (int j = 0; j < 4; j++) acc[i][j] = 0.f;

    for (int k0 = 0; k0 < 128; k0 += TK) {
        float4 av = make_float4(0.f, 0.f, 0.f, 0.f);
        if (ar < TM && (m0 + ar) < M)
            av = *(const float4*)&A[(size_t)(m0 + ar) * 512 + kbase + k0 + ac];
        float4 bv = *(const float4*)&W[(size_t)(wrow + kbase + k0 + br) * 512 + n0 + bc];

        __syncthreads();
        if (ar < TM) {
            As[ac + 0][ar] = av.x;
            As[ac + 1][ar] = av.y;
            As[ac + 2][ar] = av.z;
            As[ac + 3][ar] = av.w;
        }
        *(float4*)&Bs[br][bc] = bv;
        __syncthreads();

        #pragma unroll
        for (int k = 0; k < TK; k++) {
            float2 a2 = *(const float2*)&As[k][my];
            float4 b4 = *(const float4*)&Bs[k][mx];
            acc[0][0] += a2.x * b4.x; acc[0][1] += a2.x * b4.y;
            acc[0][2] += a2.x * b4.z; acc[0][3] += a2.x * b4.w;
            acc[1][0] += a2.y * b4.x; acc[1][1] += a2.y * b4.y;
            acc[1][2] += a2.y * b4.z; acc[1][3] += a2.y * b4.w;
        }
    }

    #pragma unroll
    for (int i = 0; i < 2; i++) {
        int row = m0 + my + i;
        if (row < M) {
            *(float4*)&P[((size_t)kz * PROWS + tbase + row) * 512 + n0 + mx] =
                make_float4(acc[i][0], acc[i][1], acc[i][2], acc[i][3]);
        }
    }
}

// T[r] built from P:
//   r < 168          : T01[r] = sum_kz P[kz][r/24] + sum_kz P[kz][7 + r%24]
//   168 <= r < 456   : T2 row   = sum_kz P[kz][r - 137]          (31 + r-168)
//   r >= 456         : Tp row   = sum_kz P[kz][r - 137] + bias   (319 + r-456)
__global__ __launch_bounds__(256) void te_reduce(
    const float* __restrict__ P, const float* __restrict__ bias,
    float* __restrict__ T)
{
    const int idx4 = blockIdx.x * 256 + threadIdx.x;   // float4 index, < 320512
    if (idx4 >= TROWS * 128) return;
    const int row = idx4 >> 7;
    const int d4  = idx4 & 127;

    const float4* P4 = (const float4*)P;
    const size_t stride4 = (size_t)PROWS * 128;

    float4 s;
    if (row < 168) {
        const int i0 = row / 24;
        const int i1 = row - i0 * 24;
        const int r0 = i0 * 128 + d4;
        const int r1 = (7 + i1) * 128 + d4;
        s = P4[r0];
        float4 v = P4[r1];
        s.x += v.x; s.y += v.y; s.z += v.z; s.w += v.w;
        #pragma unroll
        for (int kz = 1; kz < KSPLIT; kz++) {
            float4 a = P4[kz * stride4 + r0];
            float4 b = P4[kz * stride4 + r1];
            s.x += a.x + b.x; s.y += a.y + b.y;
            s.z += a.z + b.z; s.w += a.w + b.w;
        }
    } else {
        const int ri = (row - 137) * 128 + d4;
        s = P4[ri];
        #pragma unroll
        for (int kz = 1; kz < KSPLIT; kz++) {
            float4 v = P4[kz * stride4 + ri];
            s.x += v.x; s.y += v.y; s.z += v.z; s.w += v.w;
        }
        if (row >= 456) {
            float4 bb = ((const float4*)bias)[d4];
            s.x += bb.x; s.y += bb.y; s.z += bb.z; s.w += bb.w;
        }
    }
    ((float4*)T)[idx4] = s;
}

// l-major gather: one block per (o, l). 16 iterations over b (2 rows/iter).
// out[o, b, l, :] = T01[i0*24+i1] + T2[i2] + Tp[l]
// Tp[l] is loop-invariant (1 register load); T01+T2 (920 KB) stay L2-resident.
__global__ __launch_bounds__(256) void te_gather_add(
    const int* __restrict__ in0, const int* __restrict__ tg0,
    const int* __restrict__ in1, const int* __restrict__ tg1,
    const int* __restrict__ in2, const int* __restrict__ tg2,
    const float* __restrict__ T, float* __restrict__ out)
{
    __shared__ int s_i01[32];
    __shared__ int s_i2[32];

    const int bid = blockIdx.x;        // 0..4095
    const int o   = bid >> 11;         // 0..1
    const int l   = bid & 2047;
    const int tid = threadIdx.x;

    if (tid < 32) {
        const int* __restrict__ p0 = o ? tg0 : in0;
        const int* __restrict__ p1 = o ? tg1 : in1;
        const int* __restrict__ p2 = o ? tg2 : in2;
        const int i0 = p0[tid * 2048 + l];
        const int i1 = p1[tid * 2048 + l];
        s_i01[tid] = i0 * 24 + i1;
        s_i2[tid]  = p2[tid * 2048 + l];
    }
    __syncthreads();

    const int d4 = tid & 127;          // float4 index within the 512-wide row
    const int bo = tid >> 7;           // 0..1 : which of the 2 b-rows this iter

    const float4* __restrict__ T01 = (const float4*)T;                 // 168  x 128
    const float4* __restrict__ T2  = (const float4*)(T + 168 * 512);   // 288  x 128
    const float4* __restrict__ Tp  = (const float4*)(T + 456 * 512);   // 2048 x 128

    const float4 p = Tp[l * 128 + d4];

    // out float4 index for b=0: ((o*32 + b)*2048 + l)*128 + d4
    vfloat4* __restrict__ obase =
        (vfloat4*)out + ((size_t)o * 32 * 2048 + l) * 128 + d4;

    #pragma unroll 4
    for (int bi = 0; bi < 16; bi++) {
        const int b = bi * 2 + bo;
        const float4 a = T01[s_i01[b] * 128 + d4];
        const float4 c = T2 [s_i2 [b] * 128 + d4];
        vfloat4 r;
        r.x = a.x + c.x + p.x;
        r.y = a.y + c.y + p.y;
        r.z = a.z + c.z + p.z;
        r.w = a.w + c.w + p.w;
        // Non-temporal: keep the 268 MB output stream from evicting T01/T2 out of L2.
        __builtin_nontemporal_store(r, obase + (size_t)b * 2048 * 128);
    }
}

extern "C" void kernel_launch(void* const* d_in, const int* in_sizes, int n_in,
                              void* d_out, int out_size, void* d_ws, size_t ws_size,
                              hipStream_t stream) {
    const int*   in0  = (const int*)  d_in[0];
    const int*   tg0  = (const int*)  d_in[1];
    const int*   in1  = (const int*)  d_in[2];
    const int*   tg1  = (const int*)  d_in[3];
    const int*   in2  = (const int*)  d_in[4];
    const int*   tg2  = (const int*)  d_in[5];
    const float* emb0 = (const float*)d_in[6];
    const float* emb1 = (const float*)d_in[7];
    const float* emb2 = (const float*)d_in[8];
    const float* pe   = (const float*)d_in[9];
    const float* W    = (const float*)d_in[10];
    const float* bias = (const float*)d_in[11];
    float* out = (float*)d_out;
    float* T   = (float*)d_ws;                      // 2504 x 512
    float* P   = T + (size_t)TROWS * 512;           // 4 x 2367 x 512

    // 1) split-K partial GEMMs for the projected tables
    dim3 ggrid(8, 75, KSPLIT);
    te_gemm_partial<<<ggrid, 256, 0, stream>>>(emb0, emb1, emb2, pe, W, P);

    // 2) reduce partials (+ bias into Tp rows, + T01 = T0[i0]+T1[i1] combine)
    te_reduce<<<(TROWS * 128 + 255) / 256, 256, 0, stream>>>(P, bias, T);

    // 3) l-major gather-add into both outputs
    te_gather_add<<<4096, 256, 0, stream>>>(in0, tg0, in1, tg1, in2, tg2, T, out);
}

// Round 2
// 326.264 us; speedup vs baseline: 1.1034x; 1.0319x over previous
//
#include <hip/hip_runtime.h>

// TemporalEmbedding: out = concat(emb0[i0], emb1[i1], emb2[i2], pe) @ W + b
// Split-K table GEMM (partials) -> reduce(+bias, +T01 combine) -> l-major gather-add.
//
// P row layout (2367 rows x 512), written by te_gemm_partial:
//   rows 0..6     : T0 = emb0 @ W[0:512]
//   rows 7..30    : T1 = emb1 @ W[512:1024]
//   rows 31..318  : T2 = emb2 @ W[1024:1536]
//   rows 319..2366: Tp = pe[:2048] @ W[1536:2048]   (bias added in reduce)
//
// T row layout (2504 rows x 512), written by te_reduce:
//   rows 0..167   : T01[i0*24+i1] = T0[i0] + T1[i1]   (344 KB)
//   rows 168..455 : T2                                  (576 KB)
//   rows 456..2503: Tp + bias                           (4 MB)
// Hot random-read set for the gather = T01+T2 = 920 KB -> L2-resident per XCD.
//
// R2 change: GEMM register blocking 2x4 -> 4x4 (tile 32x64 -> 64x64).
//   Per wave-k: 2x ds_read_b128 (24 cyc) feeds 16 FMA (32 cyc) -> VALU-bound
//   (was 8 FMA per b64+b128 = LDS-issue-bound). Halves LDS traffic and barriers.
//
// Workspace (floats):
//   T at 0                 : 2504 x 512             (5.1 MB)
//   P at 2504*512          : 4 x 2367 x 512         (19.4 MB)  split-K partials

#define TM 64
#define TN 64
#define TK 16
#define KSPLIT 4
#define PROWS 2367
#define TROWS 2504

// clang-native vector type for __builtin_nontemporal_store
typedef float vfloat4 __attribute__((ext_vector_type(4)));

__global__ __launch_bounds__(256) void te_gemm_partial(
    const float* __restrict__ emb0, const float* __restrict__ emb1,
    const float* __restrict__ emb2, const float* __restrict__ pe,
    const float* __restrict__ W, float* __restrict__ P)
{
    // grid: x = 8 n-tiles, y = 39 m-tiles (1 + 1 + 5 + 32), z = 4 k-splits
    __shared__ float As[TK][TM + 4];   // [k][m]  row stride 272 B (16B-aligned)
    __shared__ float Bs[TK][TN + 4];   // [k][n]

    const int nt  = blockIdx.x;
    const int mt  = blockIdx.y;
    const int kz  = blockIdx.z;
    const int tid = threadIdx.x;

    const float* A; int M; int m0; int wrow; int tbase;
    if (mt == 0)       { A = emb0; M = 7;    m0 = 0;            wrow = 0;    tbase = 0;   }
    else if (mt == 1)  { A = emb1; M = 24;   m0 = 0;            wrow = 512;  tbase = 7;   }
    else if (mt < 7)   { A = emb2; M = 288;  m0 = (mt-2)*TM;    wrow = 1024; tbase = 31;  }
    else               { A = pe;   M = 2048; m0 = (mt-7)*TM;    wrow = 1536; tbase = 319; }

    const int n0 = nt * TN;
    const int kbase = kz * 128;   // this block's K range: [kbase, kbase+128)

    // staging coords
    const int ar = tid >> 2;          // 0..63 : A row within tile
    const int ac = (tid & 3) * 4;     // k offset (float4)
    const int br = tid >> 4;          // 0..15 : B k-row
    const int bc = (tid & 15) * 4;    // n offset (float4)

    // compute coords: 4x4 outputs per thread
    const int my = (tid >> 4) * 4;    // 0..60
    const int mx = (tid & 15) * 4;    // 0..60

    const bool a_valid = (m0 + ar) < M;
    const float* Aptr = A + (size_t)(m0 + ar) * 512 + kbase + ac;
    const float* Wptr = W + (size_t)(wrow + kbase + br) * 512 + n0 + bc;

    float acc[4][4];
    #pragma unroll
    for (int i = 0; i < 4; i++)
        #pragma unroll
        for (int j = 0; j < 4; j++) acc[i][j] = 0.f;

    for (int k0 = 0; k0 < 128; k0 += TK) {
        float4 av = make_float4(0.f, 0.f, 0.f, 0.f);
        if (a_valid) av = *(const float4*)(Aptr + k0);
        float4 bv = *(const float4*)(Wptr + (size_t)k0 * 512);

        __syncthreads();
        As[ac + 0][ar] = av.x;
        As[ac + 1][ar] = av.y;
        As[ac + 2][ar] = av.z;
        As[ac + 3][ar] = av.w;
        *(float4*)&Bs[br][bc] = bv;
        __syncthreads();

        #pragma unroll
        for (int k = 0; k < TK; k++) {
            float4 a4 = *(const float4*)&As[k][my];
            float4 b4 = *(const float4*)&Bs[k][mx];
            acc[0][0] += a4.x * b4.x; acc[0][1] += a4.x * b4.y;
            acc[0][2] += a4.x * b4.z; acc[0][3] += a4.x * b4.w;
            acc[1][0] += a4.y * b4.x; acc[1][1] += a4.y * b4.y;
            acc[1][2] += a4.y * b4.z; acc[1][3] += a4.y * b4.w;
            acc[2][0] += a4.z * b4.x; acc[2][1] += a4.z * b4.y;
            acc[2][2] += a4.z * b4.z; acc[2][3] += a4.z * b4.w;
            acc[3][0] += a4.w * b4.x; acc[3][1] += a4.w * b4.y;
            acc[3][2] += a4.w * b4.z; acc[3][3] += a4.w * b4.w;
        }
    }

    #pragma unroll
    for (int i = 0; i < 4; i++) {
        int row = m0 + my + i;
        if (row < M) {
            *(float4*)&P[((size_t)kz * PROWS + tbase + row) * 512 + n0 + mx] =
                make_float4(acc[i][0], acc[i][1], acc[i][2], acc[i][3]);
        }
    }
}

// T[r] built from P:
//   r < 168          : T01[r] = sum_kz P[kz][r/24] + sum_kz P[kz][7 + r%24]
//   168 <= r < 456   : T2 row   = sum_kz P[kz][r - 137]          (31 + r-168)
//   r >= 456         : Tp row   = sum_kz P[kz][r - 137] + bias   (319 + r-456)
__global__ __launch_bounds__(256) void te_reduce(
    const float* __restrict__ P, const float* __restrict__ bias,
    float* __restrict__ T)
{
    const int idx4 = blockIdx.x * 256 + threadIdx.x;   // float4 index, < 320512
    if (idx4 >= TROWS * 128) return;
    const int row = idx4 >> 7;
    const int d4  = idx4 & 127;

    const float4* P4 = (const float4*)P;
    const size_t stride4 = (size_t)PROWS * 128;

    float4 s;
    if (row < 168) {
        const int i0 = row / 24;
        const int i1 = row - i0 * 24;
        const int r0 = i0 * 128 + d4;
        const int r1 = (7 + i1) * 128 + d4;
        s = P4[r0];
        float4 v = P4[r1];
        s.x += v.x; s.y += v.y; s.z += v.z; s.w += v.w;
        #pragma unroll
        for (int kz = 1; kz < KSPLIT; kz++) {
            float4 a = P4[kz * stride4 + r0];
            float4 b = P4[kz * stride4 + r1];
            s.x += a.x + b.x; s.y += a.y + b.y;
            s.z += a.z + b.z; s.w += a.w + b.w;
        }
    } else {
        const int ri = (row - 137) * 128 + d4;
        s = P4[ri];
        #pragma unroll
        for (int kz = 1; kz < KSPLIT; kz++) {
            float4 v = P4[kz * stride4 + ri];
            s.x += v.x; s.y += v.y; s.z += v.z; s.w += v.w;
        }
        if (row >= 456) {
            float4 bb = ((const float4*)bias)[d4];
            s.x += bb.x; s.y += bb.y; s.z += bb.z; s.w += bb.w;
        }
    }
    ((float4*)T)[idx4] = s;
}

// l-major gather: one block per (o, l). 16 iterations over b (2 rows/iter).
// out[o, b, l, :] = T01[i0*24+i1] + T2[i2] + Tp[l]
// Tp[l] is loop-invariant (1 register load); T01+T2 (920 KB) stay L2-resident.
__global__ __launch_bounds__(256) void te_gather_add(
    const int* __restrict__ in0, const int* __restrict__ tg0,
    const int* __restrict__ in1, const int* __restrict__ tg1,
    const int* __restrict__ in2, const int* __restrict__ tg2,
    const float* __restrict__ T, float* __restrict__ out)
{
    __shared__ int s_i01[32];
    __shared__ int s_i2[32];

    const int bid = blockIdx.x;        // 0..4095
    const int o   = bid >> 11;         // 0..1
    const int l   = bid & 2047;
    const int tid = threadIdx.x;

    if (tid < 32) {
        const int* __restrict__ p0 = o ? tg0 : in0;
        const int* __restrict__ p1 = o ? tg1 : in1;
        const int* __restrict__ p2 = o ? tg2 : in2;
        const int i0 = p0[tid * 2048 + l];
        const int i1 = p1[tid * 2048 + l];
        s_i01[tid] = i0 * 24 + i1;
        s_i2[tid]  = p2[tid * 2048 + l];
    }
    __syncthreads();

    const int d4 = tid & 127;          // float4 index within the 512-wide row
    const int bo = tid >> 7;           // 0..1 : which of the 2 b-rows this iter

    const float4* __restrict__ T01 = (const float4*)T;                 // 168  x 128
    const float4* __restrict__ T2  = (const float4*)(T + 168 * 512);   // 288  x 128
    const float4* __restrict__ Tp  = (const float4*)(T + 456 * 512);   // 2048 x 128

    const float4 p = Tp[l * 128 + d4];

    // out float4 index for b=0: ((o*32 + b)*2048 + l)*128 + d4
    vfloat4* __restrict__ obase =
        (vfloat4*)out + ((size_t)o * 32 * 2048 + l) * 128 + d4;

    #pragma unroll 4
    for (int bi = 0; bi < 16; bi++) {
        const int b = bi * 2 + bo;
        const float4 a = T01[s_i01[b] * 128 + d4];
        const float4 c = T2 [s_i2 [b] * 128 + d4];
        vfloat4 r;
        r.x = a.x + c.x + p.x;
        r.y = a.y + c.y + p.y;
        r.z = a.z + c.z + p.z;
        r.w = a.w + c.w + p.w;
        // Non-temporal: keep the 268 MB output stream from evicting T01/T2 out of L2.
        __builtin_nontemporal_store(r, obase + (size_t)b * 2048 * 128);
    }
}

extern "C" void kernel_launch(void* const* d_in, const int* in_sizes, int n_in,
                              void* d_out, int out_size, void* d_ws, size_t ws_size,
                              hipStream_t stream) {
    const int*   in0  = (const int*)  d_in[0];
    const int*   tg0  = (const int*)  d_in[1];
    const int*   in1  = (const int*)  d_in[2];
    const int*   tg1  = (const int*)  d_in[3];
    const int*   in2  = (const int*)  d_in[4];
    const int*   tg2  = (const int*)  d_in[5];
    const float* emb0 = (const float*)d_in[6];
    const float* emb1 = (const float*)d_in[7];
    const float* emb2 = (const float*)d_in[8];
    const float* pe   = (const float*)d_in[9];
    const float* W    = (const float*)d_in[10];
    const float* bias = (const float*)d_in[11];
    float* out = (float*)d_out;
    float* T   = (float*)d_ws;                      // 2504 x 512
    float* P   = T + (size_t)TROWS * 512;           // 4 x 2367 x 512

    // 1) split-K partial GEMMs for the projected tables
    dim3 ggrid(8, 39, KSPLIT);
    te_gemm_partial<<<ggrid, 256, 0, stream>>>(emb0, emb1, emb2, pe, W, P);

    // 2) reduce partials (+ bias into Tp rows, + T01 = T0[i0]+T1[i1] combine)
    te_reduce<<<(TROWS * 128 + 255) / 256, 256, 0, stream>>>(P, bias, T);

    // 3) l-major gather-add into both outputs
    te_gather_add<<<4096, 256, 0, stream>>>(in0, tg0, in1, tg1, in2, tg2, T, out);
}